// Round 8
// baseline (114.037 us; speedup 1.0000x reference)
//
#include <hip/hip_runtime.h>
#include <math.h>

// N_NODES=100000, N_MOTIFS=1000000, R_DIM=1, D_DIM=64, N_GRAPHS=128.
// f32 row = 256 B; fp8 row = 64 B (16 u32 words).
//
// Model: R6 established gather-byte reduction (fp8) as the big lever
// (153->110). R7 showed T-line duplication was a non-issue. Remaining gap
// vs ~55us HBM roofline is latency/turnover: 125k short waves, no
// cross-motif pipelining. R8: persistent grid-stride waves + 2-stage
// index prefetch pipeline.

typedef float    f32x4 __attribute__((ext_vector_type(4)));
typedef float    f32x2 __attribute__((ext_vector_type(2)));
typedef unsigned u32x2 __attribute__((ext_vector_type(2)));

__global__ void zero_kernel(float* __restrict__ node_sum, int N,
                            float* __restrict__ out, int G) {
    int i = blockIdx.x * blockDim.x + threadIdx.x;
    if (i < N) node_sum[i] = 0.0f;
    if (i < G) out[i] = 0.0f;
}

// Convert Q,K (f32) -> fp8 e4m3 tables in ws. i indexes groups of 8 floats.
__global__ __launch_bounds__(256) void prep_kernel(
    const f32x4* __restrict__ Q4, const f32x4* __restrict__ K4,
    u32x2* __restrict__ Qf, u32x2* __restrict__ Kf, int n8)
{
    int i = blockIdx.x * blockDim.x + threadIdx.x;
    if (i >= n8) return;
    f32x4 a = __builtin_nontemporal_load(&Q4[2 * i]);
    f32x4 b = __builtin_nontemporal_load(&Q4[2 * i + 1]);
    u32x2 w;
    int lo = __builtin_amdgcn_cvt_pk_fp8_f32(a.x, a.y, 0, false);
    lo     = __builtin_amdgcn_cvt_pk_fp8_f32(a.z, a.w, lo, true);
    int hi = __builtin_amdgcn_cvt_pk_fp8_f32(b.x, b.y, 0, false);
    hi     = __builtin_amdgcn_cvt_pk_fp8_f32(b.z, b.w, hi, true);
    w.x = (unsigned)lo; w.y = (unsigned)hi;
    Qf[i] = w;

    a = __builtin_nontemporal_load(&K4[2 * i]);
    b = __builtin_nontemporal_load(&K4[2 * i + 1]);
    lo = __builtin_amdgcn_cvt_pk_fp8_f32(a.x, a.y, 0, false);
    lo = __builtin_amdgcn_cvt_pk_fp8_f32(a.z, a.w, lo, true);
    hi = __builtin_amdgcn_cvt_pk_fp8_f32(b.x, b.y, 0, false);
    hi = __builtin_amdgcn_cvt_pk_fp8_f32(b.z, b.w, hi, true);
    w.x = (unsigned)lo; w.y = (unsigned)hi;
    Kf[i] = w;
}

// Persistent motif pass: 8 lanes/motif, grid-stride over motif groups with
// 2-stage pipeline (next iteration's indices prefetched during current
// decode/compute). Consecutive groups in a wave -> consecutive motifs, so
// T nt-loads stay line-coalesced.
__global__ __launch_bounds__(256) void motif_kernel(
    const unsigned* __restrict__ Qf, const unsigned* __restrict__ Kf,
    const f32x4* __restrict__ T4, const float* __restrict__ beta_p,
    const int* __restrict__ c3, const int* __restrict__ u3,
    const int* __restrict__ v3, float* __restrict__ node_sum,
    int M, float inv_scale, int nGroups)
{
    int tid = blockIdx.x * 256 + threadIdx.x;
    int grp = tid >> 3;
    int g = tid & 7;
    if (grp >= M) return;

    const float beta_scale = beta_p[0] * inv_scale;

    int m = grp;
    int c = c3[m], u = u3[m], v = v3[m];

    while (true) {
        // data loads for current motif
        const f32x4* tp = T4 + (size_t)m * 16 + g;
        f32x4 t0 = __builtin_nontemporal_load(tp);      // elems 4g..4g+3
        f32x4 t1 = __builtin_nontemporal_load(tp + 8);  // elems 32+4g..
        unsigned qw0  = Qf[(size_t)c * 16 + g];
        unsigned qw1  = Qf[(size_t)c * 16 + 8 + g];
        unsigned kuw0 = Kf[(size_t)u * 16 + g];
        unsigned kuw1 = Kf[(size_t)u * 16 + 8 + g];
        unsigned kvw0 = Kf[(size_t)v * 16 + g];
        unsigned kvw1 = Kf[(size_t)v * 16 + 8 + g];

        // prefetch next iteration's indices (hides idx->gather dependency)
        int m_next = m + nGroups;
        bool has_next = (m_next < M);
        int cn = 0, un = 0, vn = 0;
        if (has_next) { cn = c3[m_next]; un = u3[m_next]; vn = v3[m_next]; }

        f32x2 q01  = __builtin_amdgcn_cvt_pk_f32_fp8((int)qw0,  false);
        f32x2 q23  = __builtin_amdgcn_cvt_pk_f32_fp8((int)qw0,  true);
        f32x2 q45  = __builtin_amdgcn_cvt_pk_f32_fp8((int)qw1,  false);
        f32x2 q67  = __builtin_amdgcn_cvt_pk_f32_fp8((int)qw1,  true);
        f32x2 ku01 = __builtin_amdgcn_cvt_pk_f32_fp8((int)kuw0, false);
        f32x2 ku23 = __builtin_amdgcn_cvt_pk_f32_fp8((int)kuw0, true);
        f32x2 ku45 = __builtin_amdgcn_cvt_pk_f32_fp8((int)kuw1, false);
        f32x2 ku67 = __builtin_amdgcn_cvt_pk_f32_fp8((int)kuw1, true);
        f32x2 kv01 = __builtin_amdgcn_cvt_pk_f32_fp8((int)kvw0, false);
        f32x2 kv23 = __builtin_amdgcn_cvt_pk_f32_fp8((int)kvw0, true);
        f32x2 kv45 = __builtin_amdgcn_cvt_pk_f32_fp8((int)kvw1, false);
        f32x2 kv67 = __builtin_amdgcn_cvt_pk_f32_fp8((int)kvw1, true);

        float p =
            q01.x * fmaf(ku01.x, kv01.x, t0.x)
          + q01.y * fmaf(ku01.y, kv01.y, t0.y)
          + q23.x * fmaf(ku23.x, kv23.x, t0.z)
          + q23.y * fmaf(ku23.y, kv23.y, t0.w)
          + q45.x * fmaf(ku45.x, kv45.x, t1.x)
          + q45.y * fmaf(ku45.y, kv45.y, t1.y)
          + q67.x * fmaf(ku67.x, kv67.x, t1.z)
          + q67.y * fmaf(ku67.y, kv67.y, t1.w);

        // reduce across the 8-lane group
        #pragma unroll
        for (int off = 4; off > 0; off >>= 1)
            p += __shfl_xor(p, off);

        if (g == 0) {
            // |bell| <~ 8.5 -> exp safe in f32, no max-shift pass needed
            atomicAdd(&node_sum[c], __expf(beta_scale * p));
        }

        if (!has_next) break;
        m = m_next; c = cn; u = un; v = vn;
    }
}

// Per node: lse = log(sum) (or 0 if empty). LDS per-graph reduction (batch is
// sorted -> each 256-node block spans ~1-2 graphs), then scaled atomicAdd.
__global__ __launch_bounds__(256) void node_kernel(
    const float* __restrict__ node_sum, const int* __restrict__ batch,
    const float* __restrict__ lam_p, const float* __restrict__ beta_p,
    float* __restrict__ out, int N, int G)
{
    extern __shared__ float gacc[];
    for (int j = threadIdx.x; j < G; j += blockDim.x) gacc[j] = 0.0f;
    __syncthreads();

    int i = blockIdx.x * blockDim.x + threadIdx.x;
    if (i < N) {
        float s = node_sum[i];
        if (s > 0.0f) {
            atomicAdd(&gacc[batch[i]], logf(s));
        }
    }
    __syncthreads();

    float coef = lam_p[0] / beta_p[0];
    for (int j = threadIdx.x; j < G; j += blockDim.x) {
        float v = gacc[j];
        if (v != 0.0f) atomicAdd(&out[j], coef * v);
    }
}

extern "C" void kernel_launch(void* const* d_in, const int* in_sizes, int n_in,
                              void* d_out, int out_size, void* d_ws, size_t ws_size,
                              hipStream_t stream) {
    const float* Q    = (const float*)d_in[0];
    const float* K    = (const float*)d_in[1];
    const float* T    = (const float*)d_in[2];
    const float* lam  = (const float*)d_in[3];
    const float* beta = (const float*)d_in[4];
    const int* c3     = (const int*)d_in[5];
    const int* u3     = (const int*)d_in[6];
    const int* v3     = (const int*)d_in[7];
    const int* batch  = (const int*)d_in[8];

    const int M = in_sizes[5];          // 1,000,000
    const int N = in_sizes[8];          // 100,000
    const int G = out_size;             // 128
    const int RD = in_sizes[0] / N;     // R*D = 64
    const int n8 = in_sizes[0] / 8;     // 8-float groups per table
    const float inv_scale = 1.0f / sqrtf((float)RD);

    // ws layout: node_sum (N f32) | Qf (N*RD fp8) | Kf (N*RD fp8)
    float* node_sum = (float*)d_ws;
    size_t off = (((size_t)N * sizeof(float)) + 1023) & ~(size_t)1023;
    unsigned* Qf = (unsigned*)((char*)d_ws + off);
    unsigned* Kf = Qf + (size_t)n8 * 2;
    float* out = (float*)d_out;

    int zmax = (N > G) ? N : G;
    zero_kernel<<<(zmax + 255) / 256, 256, 0, stream>>>(node_sum, N, out, G);

    prep_kernel<<<(n8 + 255) / 256, 256, 0, stream>>>(
        (const f32x4*)Q, (const f32x4*)K, (u32x2*)Qf, (u32x2*)Kf, n8);

    // persistent waves: 2048 blocks = 524288 threads = 65536 groups,
    // ~15 motifs per group
    const int mblocks = 2048;
    const int nGroups = mblocks * 256 / 8;
    motif_kernel<<<mblocks, 256, 0, stream>>>(
        Qf, Kf, (const f32x4*)T, beta, c3, u3, v3, node_sum,
        M, inv_scale, nGroups);

    node_kernel<<<(N + 255) / 256, 256, G * sizeof(float), stream>>>(
        node_sum, batch, lam, beta, out, N, G);
}

// Round 9
// 112.343 us; speedup vs baseline: 1.0151x; 1.0151x over previous
//
#include <hip/hip_runtime.h>
#include <math.h>

// N_NODES=100000, N_MOTIFS=1000000, R_DIM=1, D_DIM=64, N_GRAPHS=128.
// f32 row = 256 B; fp8 row = 64 B (16 u32 words).
//
// Model (R3 FETCH evidence): T's 256 MB/pass stream thrashes L2+L3, so fp8
// table gathers miss to HBM as random 128-B lines (~265 MB) -> motif ~91us.
// R9: T loads via inline asm with sc0 sc1 nt (system-scope, no L2 allocate,
// evict-first) so the 12.8 MB fp8 tables stay cache-resident.

typedef float    f32x4 __attribute__((ext_vector_type(4)));
typedef float    f32x2 __attribute__((ext_vector_type(2)));
typedef unsigned u32x2 __attribute__((ext_vector_type(2)));

__global__ void zero_kernel(float* __restrict__ node_sum, int N,
                            float* __restrict__ out, int G) {
    int i = blockIdx.x * blockDim.x + threadIdx.x;
    if (i < N) node_sum[i] = 0.0f;
    if (i < G) out[i] = 0.0f;
}

// Convert Q,K (f32) -> fp8 e4m3 tables in ws. i indexes groups of 8 floats.
__global__ __launch_bounds__(256) void prep_kernel(
    const f32x4* __restrict__ Q4, const f32x4* __restrict__ K4,
    u32x2* __restrict__ Qf, u32x2* __restrict__ Kf, int n8)
{
    int i = blockIdx.x * blockDim.x + threadIdx.x;
    if (i >= n8) return;
    f32x4 a = __builtin_nontemporal_load(&Q4[2 * i]);
    f32x4 b = __builtin_nontemporal_load(&Q4[2 * i + 1]);
    u32x2 w;
    int lo = __builtin_amdgcn_cvt_pk_fp8_f32(a.x, a.y, 0, false);
    lo     = __builtin_amdgcn_cvt_pk_fp8_f32(a.z, a.w, lo, true);
    int hi = __builtin_amdgcn_cvt_pk_fp8_f32(b.x, b.y, 0, false);
    hi     = __builtin_amdgcn_cvt_pk_fp8_f32(b.z, b.w, hi, true);
    w.x = (unsigned)lo; w.y = (unsigned)hi;
    Qf[i] = w;

    a = __builtin_nontemporal_load(&K4[2 * i]);
    b = __builtin_nontemporal_load(&K4[2 * i + 1]);
    lo = __builtin_amdgcn_cvt_pk_fp8_f32(a.x, a.y, 0, false);
    lo = __builtin_amdgcn_cvt_pk_fp8_f32(a.z, a.w, lo, true);
    hi = __builtin_amdgcn_cvt_pk_fp8_f32(b.x, b.y, 0, false);
    hi = __builtin_amdgcn_cvt_pk_fp8_f32(b.z, b.w, hi, true);
    w.x = (unsigned)lo; w.y = (unsigned)hi;
    Kf[i] = w;
}

// Fused motif pass: 8 lanes/motif, lane g owns elems {4g..4g+3, 32+4g..35+4g}.
// T loads: asm global_load_dwordx4 with sc0 sc1 nt -> no cache allocation,
// tables keep L2/L3 residency. fp8 gathers: normal cached loads.
__global__ __launch_bounds__(256) void motif_kernel(
    const unsigned* __restrict__ Qf, const unsigned* __restrict__ Kf,
    const f32x4* __restrict__ T4, const float* __restrict__ beta_p,
    const int* __restrict__ c3, const int* __restrict__ u3,
    const int* __restrict__ v3, float* __restrict__ node_sum,
    int M, float inv_scale)
{
    long long tid = (long long)blockIdx.x * 256 + threadIdx.x;
    int m = (int)(tid >> 3);
    int g = (int)(tid & 7);
    if (m >= M) return;

    int c = c3[m];
    int u = u3[m];
    int v = v3[m];

    // T: streaming loads with strongest no-cache policy (sc0 sc1 nt).
    const f32x4* tp = T4 + (size_t)m * 16 + g;
    f32x4 t0, t1;
    asm volatile("global_load_dwordx4 %0, %1, off sc0 sc1 nt"
                 : "=v"(t0) : "v"(tp));
    asm volatile("global_load_dwordx4 %0, %1, off sc0 sc1 nt"
                 : "=v"(t1) : "v"(tp + 8));

    unsigned qw0  = Qf[(size_t)c * 16 + g];
    unsigned qw1  = Qf[(size_t)c * 16 + 8 + g];
    unsigned kuw0 = Kf[(size_t)u * 16 + g];
    unsigned kuw1 = Kf[(size_t)u * 16 + 8 + g];
    unsigned kvw0 = Kf[(size_t)v * 16 + g];
    unsigned kvw1 = Kf[(size_t)v * 16 + 8 + g];

    // Wait for the asm T loads (and everything else) before use; the memory
    // clobber keeps the gather loads above this point, sched_barrier keeps
    // the consumers below (guide rule #18).
    asm volatile("s_waitcnt vmcnt(0)" ::: "memory");
    __builtin_amdgcn_sched_barrier(0);

    f32x2 q01  = __builtin_amdgcn_cvt_pk_f32_fp8((int)qw0,  false);
    f32x2 q23  = __builtin_amdgcn_cvt_pk_f32_fp8((int)qw0,  true);
    f32x2 q45  = __builtin_amdgcn_cvt_pk_f32_fp8((int)qw1,  false);
    f32x2 q67  = __builtin_amdgcn_cvt_pk_f32_fp8((int)qw1,  true);
    f32x2 ku01 = __builtin_amdgcn_cvt_pk_f32_fp8((int)kuw0, false);
    f32x2 ku23 = __builtin_amdgcn_cvt_pk_f32_fp8((int)kuw0, true);
    f32x2 ku45 = __builtin_amdgcn_cvt_pk_f32_fp8((int)kuw1, false);
    f32x2 ku67 = __builtin_amdgcn_cvt_pk_f32_fp8((int)kuw1, true);
    f32x2 kv01 = __builtin_amdgcn_cvt_pk_f32_fp8((int)kvw0, false);
    f32x2 kv23 = __builtin_amdgcn_cvt_pk_f32_fp8((int)kvw0, true);
    f32x2 kv45 = __builtin_amdgcn_cvt_pk_f32_fp8((int)kvw1, false);
    f32x2 kv67 = __builtin_amdgcn_cvt_pk_f32_fp8((int)kvw1, true);

    float p =
        q01.x * fmaf(ku01.x, kv01.x, t0.x)
      + q01.y * fmaf(ku01.y, kv01.y, t0.y)
      + q23.x * fmaf(ku23.x, kv23.x, t0.z)
      + q23.y * fmaf(ku23.y, kv23.y, t0.w)
      + q45.x * fmaf(ku45.x, kv45.x, t1.x)
      + q45.y * fmaf(ku45.y, kv45.y, t1.y)
      + q67.x * fmaf(ku67.x, kv67.x, t1.z)
      + q67.y * fmaf(ku67.y, kv67.y, t1.w);

    // reduce across the 8-lane group (xor masks < 8 stay in-group on wave64)
    #pragma unroll
    for (int off = 4; off > 0; off >>= 1)
        p += __shfl_xor(p, off);

    if (g == 0) {
        float bell = beta_p[0] * p * inv_scale;
        // |bell| <~ 8.5 -> exp safe in f32, no max-shift pass needed
        atomicAdd(&node_sum[c], __expf(bell));
    }
}

// Per node: lse = log(sum) (or 0 if empty). LDS per-graph reduction (batch is
// sorted -> each 256-node block spans ~1-2 graphs), then scaled atomicAdd.
__global__ __launch_bounds__(256) void node_kernel(
    const float* __restrict__ node_sum, const int* __restrict__ batch,
    const float* __restrict__ lam_p, const float* __restrict__ beta_p,
    float* __restrict__ out, int N, int G)
{
    extern __shared__ float gacc[];
    for (int j = threadIdx.x; j < G; j += blockDim.x) gacc[j] = 0.0f;
    __syncthreads();

    int i = blockIdx.x * blockDim.x + threadIdx.x;
    if (i < N) {
        float s = node_sum[i];
        if (s > 0.0f) {
            atomicAdd(&gacc[batch[i]], logf(s));
        }
    }
    __syncthreads();

    float coef = lam_p[0] / beta_p[0];
    for (int j = threadIdx.x; j < G; j += blockDim.x) {
        float v = gacc[j];
        if (v != 0.0f) atomicAdd(&out[j], coef * v);
    }
}

extern "C" void kernel_launch(void* const* d_in, const int* in_sizes, int n_in,
                              void* d_out, int out_size, void* d_ws, size_t ws_size,
                              hipStream_t stream) {
    const float* Q    = (const float*)d_in[0];
    const float* K    = (const float*)d_in[1];
    const float* T    = (const float*)d_in[2];
    const float* lam  = (const float*)d_in[3];
    const float* beta = (const float*)d_in[4];
    const int* c3     = (const int*)d_in[5];
    const int* u3     = (const int*)d_in[6];
    const int* v3     = (const int*)d_in[7];
    const int* batch  = (const int*)d_in[8];

    const int M = in_sizes[5];          // 1,000,000
    const int N = in_sizes[8];          // 100,000
    const int G = out_size;             // 128
    const int RD = in_sizes[0] / N;     // R*D = 64
    const int n8 = in_sizes[0] / 8;     // 8-float groups per table
    const float inv_scale = 1.0f / sqrtf((float)RD);

    // ws layout: node_sum (N f32) | Qf (N*RD fp8) | Kf (N*RD fp8)
    float* node_sum = (float*)d_ws;
    size_t off = (((size_t)N * sizeof(float)) + 1023) & ~(size_t)1023;
    unsigned* Qf = (unsigned*)((char*)d_ws + off);
    unsigned* Kf = Qf + (size_t)n8 * 2;
    float* out = (float*)d_out;

    int zmax = (N > G) ? N : G;
    zero_kernel<<<(zmax + 255) / 256, 256, 0, stream>>>(node_sum, N, out, G);

    prep_kernel<<<(n8 + 255) / 256, 256, 0, stream>>>(
        (const f32x4*)Q, (const f32x4*)K, (u32x2*)Qf, (u32x2*)Kf, n8);

    long long total_threads = (long long)M * 8;
    int mgrid = (int)((total_threads + 255) / 256);
    motif_kernel<<<mgrid, 256, 0, stream>>>(
        Qf, Kf, (const f32x4*)T, beta, c3, u3, v3, node_sum, M, inv_scale);

    node_kernel<<<(N + 255) / 256, 256, G * sizeof(float), stream>>>(
        node_sum, batch, lam, beta, out, N, G);
}